// Round 2
// baseline (12397.854 us; speedup 1.0000x reference)
//
#include <hip/hip_runtime.h>

// ---------------- problem constants ----------------
constexpr int N  = 325;   // nodes
constexpr int B  = 64;    // batch
constexpr int T  = 12;    // encoder steps
constexpr int HZ = 12;    // decoder horizon
constexpr int U  = 64;    // rnn units
constexpr int BN = B * N; // 20800 rows
constexpr int ELLW = 352; // ELL capacity >= N

constexpr int BLK  = 1024;  // threads per block (16 waves) -- one block per batch
constexpr int ROWS = 336;   // 21*16 : per-batch rows padded to MFMA tiles
constexpr int FCH  = 32;    // feature chunk for diffusion
constexpr int SST  = 36;    // LDS row stride (floats): bank-conflict-free, 16B-aligned
constexpr size_t ZBATCH = (size_t)ROWS * 384;  // zcat u32 per batch (max K3P)

typedef __attribute__((ext_vector_type(8))) short short8;
typedef __attribute__((ext_vector_type(4))) float floatx4;

// bf16 round-to-nearest-even + hi/lo split helpers
__device__ inline unsigned short f2bf(float f) {
    unsigned u = __float_as_uint(f);
    u += 0x7fff + ((u >> 16) & 1);
    return (unsigned short)(u >> 16);
}
__device__ inline unsigned pack_hilo(float v) {
    const unsigned short hi = f2bf(v);
    const float hif = __uint_as_float(((unsigned)hi) << 16);
    const unsigned short lo = f2bf(v - hif);
    return (unsigned)hi | ((unsigned)lo << 16);
}

// ---------------- setup kernels ----------------

// Build ELL (column-major, interleaved val/col) from dense S. One wave per row.
__global__ __launch_bounds__(64)
void ell_build(const float* __restrict__ S, float2* __restrict__ ellcv,
               int* __restrict__ nnz)
{
    const int m    = blockIdx.x;
    const int lane = threadIdx.x;
    const float* __restrict__ row = S + m * N;
    int count = 0;
    for (int base = 0; base < N; base += 64) {
        const int n = base + lane;
        const float v = (n < N) ? row[n] : 0.f;
        const unsigned long long mask = __ballot(v != 0.f);
        const int pre = __popcll(mask & ((1ull << lane) - 1ull));
        if (v != 0.f) {
            const int pos = count + pre;
            ellcv[pos * N + m] = make_float2(v, __int_as_float(n));
        }
        count += __popcll(mask);
    }
    if (lane == 0) nnz[m] = count;
}

// Pre-pack weight matrix (K3 x Nout fp32) into MFMA B-fragment order, bf16 hi/lo.
__global__ __launch_bounds__(64)
void prepack_w(const float* __restrict__ W, short* __restrict__ Wh,
               short* __restrict__ Wl, int K3, int Nout, int NT)
{
    const int kc = blockIdx.x, n = blockIdx.y, lane = threadIdx.x;
    const int quad = lane >> 4, l15 = lane & 15;
    short8 hv, lv;
    #pragma unroll
    for (int j = 0; j < 8; ++j) {
        const int k   = kc * 32 + quad * 8 + j;
        const int col = n * 16 + l15;
        const float w = (k < K3) ? W[k * Nout + col] : 0.f;
        const unsigned short h = f2bf(w);
        const float hf = __uint_as_float(((unsigned)h) << 16);
        hv[j] = (short)h;
        lv[j] = (short)f2bf(w - hf);
    }
    const size_t off = ((size_t)(kc * NT + n) * 64 + lane);
    ((short8*)Wh)[off] = hv;
    ((short8*)Wl)[off] = lv;
}

// ---------------- per-batch persistent kernel ----------------

struct MegaParams {
    const float2* ellcv;
    const int*    nnz;
    const float*  inputs;
    float* h0; float* h1; float* dec_in;
    float* ru; unsigned* zcat;
    const short* Wgh[4]; const short* Wgl[4];
    const short* Wch[4]; const short* Wcl[4];
    const float* gb[4];  const float* cb[4];
    const float* pW; const float* pb;
    float* out;
};

// Sparse Chebyshev diffusion for ONE batch (whole block). Writes z=[z0|z1|z2]
// packed ushort2(bf16 hi,lo) into this batch's zcat (row stride K3P).
template<int DIN, int K3P, bool RMUL>
__device__ __forceinline__ void phaseZ(const float2* __restrict__ ellcv,
    const int* __restrict__ nnz, const float* __restrict__ x,
    const float* __restrict__ h, const float* __restrict__ ru,
    unsigned* __restrict__ zb, int b, float* __restrict__ s0,
    float* __restrict__ s1)
{
    constexpr int F = DIN + U;
    const int tid = threadIdx.x;
    const int fg  = (tid & 7) * 4;   // feature sub-offset {0,4,...,28}
    const int mi  = tid >> 3;        // 0..127 rows in parallel

    for (int fc0 = 0; fc0 < F; fc0 += FCH) {
        // load concat(x, h or r*h) chunk -> LDS; write z0 slice
        for (int idx = tid; idx < N * FCH; idx += BLK) {
            const int n  = idx >> 5;
            const int f  = idx & 31;
            const int gf = fc0 + f;
            float v = 0.f;
            if (gf < F) {
                const int row = b * N + n;
                if (gf < DIN) {
                    v = x[(size_t)row * DIN + gf];
                } else {
                    v = h[(size_t)row * U + (gf - DIN)];
                    if (RMUL) v *= ru[(size_t)row * 128 + (gf - DIN)];
                }
                if (!(RMUL && gf < DIN))       // x-part identical to gate pass
                    zb[(size_t)n * K3P + gf] = pack_hilo(v);
            }
            s0[n * SST + f] = v;
        }
        if (fc0 == 0) {
            // zero K-padding strip [3F, K3P) for valid rows
            constexpr int PAD = K3P - 3 * F;
            if constexpr (PAD > 0) {
                for (int idx = tid; idx < N * PAD; idx += BLK) {
                    const int n = idx / PAD;
                    const int c = idx - n * PAD;
                    zb[(size_t)n * K3P + 3 * F + c] = 0u;
                }
            }
            // zero MFMA tile-padding rows [N, ROWS)
            for (int idx = tid; idx < (ROWS - N) * K3P; idx += BLK)
                zb[(size_t)N * K3P + idx] = 0u;
        }
        __syncthreads();

        // z1 = S @ z0
        for (int pass = 0; pass < 3; ++pass) {
            const int m = pass * 128 + mi;
            if (m < N) {
                const int cnt = nnz[m];
                float a0 = 0.f, a1 = 0.f, a2 = 0.f, a3 = 0.f;
                #pragma unroll 4
                for (int j = 0; j < cnt; ++j) {
                    const float2 cv = ellcv[j * N + m];
                    const int col = __float_as_int(cv.y);
                    const float4 v = *(const float4*)&s0[col * SST + fg];
                    a0 += cv.x * v.x; a1 += cv.x * v.y;
                    a2 += cv.x * v.z; a3 += cv.x * v.w;
                }
                *(float4*)&s1[m * SST + fg] = make_float4(a0, a1, a2, a3);
                const float vals[4] = {a0, a1, a2, a3};
                #pragma unroll
                for (int j = 0; j < 4; ++j) {
                    const int gf = fc0 + fg + j;
                    if (gf < F) zb[(size_t)m * K3P + F + gf] = pack_hilo(vals[j]);
                }
            }
        }
        __syncthreads();

        // z2 = 2*S@z1 - z0
        for (int pass = 0; pass < 3; ++pass) {
            const int m = pass * 128 + mi;
            if (m < N) {
                const int cnt = nnz[m];
                float a0 = 0.f, a1 = 0.f, a2 = 0.f, a3 = 0.f;
                #pragma unroll 4
                for (int j = 0; j < cnt; ++j) {
                    const float2 cv = ellcv[j * N + m];
                    const int col = __float_as_int(cv.y);
                    const float4 v = *(const float4*)&s1[col * SST + fg];
                    a0 += cv.x * v.x; a1 += cv.x * v.y;
                    a2 += cv.x * v.z; a3 += cv.x * v.w;
                }
                const float4 z0v = *(const float4*)&s0[m * SST + fg];
                const float vals[4] = {2.f * a0 - z0v.x, 2.f * a1 - z0v.y,
                                       2.f * a2 - z0v.z, 2.f * a3 - z0v.w};
                #pragma unroll
                for (int j = 0; j < 4; ++j) {
                    const int gf = fc0 + fg + j;
                    if (gf < F) zb[(size_t)m * K3P + 2 * F + gf] = pack_hilo(vals[j]);
                }
            }
        }
        __syncthreads();
    }
}

// Gate MFMA for one batch: ru = sigmoid(z @ W + b). 16 waves x 16-row tiles.
template<int K3P>
__device__ __forceinline__ void phaseG(const unsigned* __restrict__ zb,
    const short8* __restrict__ Wh, const short8* __restrict__ Wl,
    const float* __restrict__ bias, float* __restrict__ ru, int b)
{
    constexpr int NT = 8, KC = K3P >> 5;
    const int tid = threadIdx.x, wave = tid >> 6, lane = tid & 63;
    const int quad = lane >> 4, l15 = lane & 15;

    for (int tile = wave; tile < ROWS / 16; tile += 16) {
        const int row0 = tile * 16;
        floatx4 acc[NT];
        #pragma unroll
        for (int n = 0; n < NT; ++n) {
            const float bv = bias[n * 16 + l15];
            acc[n] = (floatx4){bv, bv, bv, bv};
        }
        const unsigned* __restrict__ zrow = zb + (size_t)(row0 + l15) * K3P + quad * 8;
        for (int kc = 0; kc < KC; ++kc) {
            const uint4* p = (const uint4*)(zrow + kc * 32);
            const uint4 u0 = p[0], u1 = p[1];
            const unsigned uu[8] = {u0.x, u0.y, u0.z, u0.w, u1.x, u1.y, u1.z, u1.w};
            short8 ahi, alo;
            #pragma unroll
            for (int j = 0; j < 8; ++j) {
                ahi[j] = (short)(uu[j] & 0xffffu);
                alo[j] = (short)(uu[j] >> 16);
            }
            const short8* __restrict__ wh = Wh + (size_t)(kc * NT) * 64 + lane;
            const short8* __restrict__ wl = Wl + (size_t)(kc * NT) * 64 + lane;
            #pragma unroll
            for (int n = 0; n < NT; ++n) {
                const short8 bh = wh[n * 64], bl = wl[n * 64];
                acc[n] = __builtin_amdgcn_mfma_f32_16x16x32_bf16(ahi, bh, acc[n], 0, 0, 0);
                acc[n] = __builtin_amdgcn_mfma_f32_16x16x32_bf16(ahi, bl, acc[n], 0, 0, 0);
                acc[n] = __builtin_amdgcn_mfma_f32_16x16x32_bf16(alo, bh, acc[n], 0, 0, 0);
            }
        }
        #pragma unroll
        for (int n = 0; n < NT; ++n) {
            const int col = n * 16 + l15;
            #pragma unroll
            for (int r = 0; r < 4; ++r) {
                const int row = row0 + quad * 4 + r;
                if (row < N)
                    ru[(size_t)(b * N + row) * 128 + col] = 1.f / (1.f + __expf(-acc[n][r]));
            }
        }
    }
}

// Candidate MFMA for one batch: c = tanh(z@W+b); h = u*h + (1-u)*c.
// PROJ: fused out = h . pW + pb, also feeds dec_in.
template<int K3P, bool PROJ>
__device__ __forceinline__ void phaseC(const unsigned* __restrict__ zb,
    const short8* __restrict__ Wh, const short8* __restrict__ Wl,
    const float* __restrict__ bias, const float* __restrict__ ru,
    float* __restrict__ h, int b, const float* __restrict__ pW,
    const float* __restrict__ pb, float* __restrict__ outp,
    float* __restrict__ dec_in)
{
    constexpr int NT = 4, KC = K3P >> 5;
    const int tid = threadIdx.x, wave = tid >> 6, lane = tid & 63;
    const int quad = lane >> 4, l15 = lane & 15;

    for (int tile = wave; tile < ROWS / 16; tile += 16) {
        const int row0 = tile * 16;
        floatx4 acc[NT];
        #pragma unroll
        for (int n = 0; n < NT; ++n) {
            const float bv = bias[n * 16 + l15];
            acc[n] = (floatx4){bv, bv, bv, bv};
        }
        const unsigned* __restrict__ zrow = zb + (size_t)(row0 + l15) * K3P + quad * 8;
        for (int kc = 0; kc < KC; ++kc) {
            const uint4* p = (const uint4*)(zrow + kc * 32);
            const uint4 u0 = p[0], u1 = p[1];
            const unsigned uu[8] = {u0.x, u0.y, u0.z, u0.w, u1.x, u1.y, u1.z, u1.w};
            short8 ahi, alo;
            #pragma unroll
            for (int j = 0; j < 8; ++j) {
                ahi[j] = (short)(uu[j] & 0xffffu);
                alo[j] = (short)(uu[j] >> 16);
            }
            const short8* __restrict__ wh = Wh + (size_t)(kc * NT) * 64 + lane;
            const short8* __restrict__ wl = Wl + (size_t)(kc * NT) * 64 + lane;
            #pragma unroll
            for (int n = 0; n < NT; ++n) {
                const short8 bh = wh[n * 64], bl = wl[n * 64];
                acc[n] = __builtin_amdgcn_mfma_f32_16x16x32_bf16(ahi, bh, acc[n], 0, 0, 0);
                acc[n] = __builtin_amdgcn_mfma_f32_16x16x32_bf16(ahi, bl, acc[n], 0, 0, 0);
                acc[n] = __builtin_amdgcn_mfma_f32_16x16x32_bf16(alo, bh, acc[n], 0, 0, 0);
            }
        }
        float pr[4] = {0.f, 0.f, 0.f, 0.f};
        #pragma unroll
        for (int n = 0; n < NT; ++n) {
            const int col = n * 16 + l15;
            float pw = 0.f;
            if constexpr (PROJ) pw = pW[col];
            #pragma unroll
            for (int r = 0; r < 4; ++r) {
                const int row = row0 + quad * 4 + r;
                if (row < N) {
                    const size_t grow = (size_t)(b * N + row);
                    const float c  = tanhf(acc[n][r]);
                    const float ug = ru[grow * 128 + 64 + col];
                    const float hv = h[grow * 64 + col];
                    const float hn = ug * hv + (1.f - ug) * c;
                    h[grow * 64 + col] = hn;
                    if constexpr (PROJ) pr[r] += hn * pw;
                }
            }
        }
        if constexpr (PROJ) {
            #pragma unroll
            for (int r = 0; r < 4; ++r) {
                float v = pr[r];
                v += __shfl_xor(v, 1); v += __shfl_xor(v, 2);
                v += __shfl_xor(v, 4); v += __shfl_xor(v, 8);
                if (l15 == 0) {
                    const int row = row0 + quad * 4 + r;
                    if (row < N) {
                        const float o = v + pb[0];
                        outp[b * N + row]   = o;
                        dec_in[b * N + row] = o;
                    }
                }
            }
        }
    }
}

__global__ __launch_bounds__(BLK, 4)
void mega_kernel(MegaParams P)
{
    __shared__ __align__(16) float s0[N * SST];   // 46.8 KB
    __shared__ __align__(16) float s1[N * SST];   // 46.8 KB
    const int b = blockIdx.x;
    unsigned* zb = P.zcat + (size_t)b * ZBATCH;

    // zero this batch's state (per-replay reset)
    for (int i = threadIdx.x; i < N * U; i += BLK) {
        P.h0[(size_t)b * N * U + i] = 0.f;
        P.h1[(size_t)b * N * U + i] = 0.f;
    }
    for (int i = threadIdx.x; i < N; i += BLK) P.dec_in[b * N + i] = 0.f;
    __syncthreads();

    // -------- encoder --------
    for (int t = 0; t < T; ++t) {
        const float* x = P.inputs + (size_t)t * BN * 2;
        // layer 0 (din=2, K3p=224)
        phaseZ<2, 224, false>(P.ellcv, P.nnz, x, P.h0, nullptr, zb, b, s0, s1);
        phaseG<224>(zb, (const short8*)P.Wgh[0], (const short8*)P.Wgl[0], P.gb[0], P.ru, b);
        __syncthreads();
        phaseZ<2, 224, true>(P.ellcv, P.nnz, x, P.h0, P.ru, zb, b, s0, s1);
        phaseC<224, false>(zb, (const short8*)P.Wch[0], (const short8*)P.Wcl[0],
                           P.cb[0], P.ru, P.h0, b, nullptr, nullptr, nullptr, nullptr);
        __syncthreads();
        // layer 1 (din=64, K3p=384)
        phaseZ<64, 384, false>(P.ellcv, P.nnz, P.h0, P.h1, nullptr, zb, b, s0, s1);
        phaseG<384>(zb, (const short8*)P.Wgh[1], (const short8*)P.Wgl[1], P.gb[1], P.ru, b);
        __syncthreads();
        phaseZ<64, 384, true>(P.ellcv, P.nnz, P.h0, P.h1, P.ru, zb, b, s0, s1);
        phaseC<384, false>(zb, (const short8*)P.Wch[1], (const short8*)P.Wcl[1],
                           P.cb[1], P.ru, P.h1, b, nullptr, nullptr, nullptr, nullptr);
        __syncthreads();
    }
    // -------- decoder --------
    for (int hz = 0; hz < HZ; ++hz) {
        // layer 0 (din=1, K3p=224)
        phaseZ<1, 224, false>(P.ellcv, P.nnz, P.dec_in, P.h0, nullptr, zb, b, s0, s1);
        phaseG<224>(zb, (const short8*)P.Wgh[2], (const short8*)P.Wgl[2], P.gb[2], P.ru, b);
        __syncthreads();
        phaseZ<1, 224, true>(P.ellcv, P.nnz, P.dec_in, P.h0, P.ru, zb, b, s0, s1);
        phaseC<224, false>(zb, (const short8*)P.Wch[2], (const short8*)P.Wcl[2],
                           P.cb[2], P.ru, P.h0, b, nullptr, nullptr, nullptr, nullptr);
        __syncthreads();
        // layer 1 (din=64, K3p=384) + fused projection
        phaseZ<64, 384, false>(P.ellcv, P.nnz, P.h0, P.h1, nullptr, zb, b, s0, s1);
        phaseG<384>(zb, (const short8*)P.Wgh[3], (const short8*)P.Wgl[3], P.gb[3], P.ru, b);
        __syncthreads();
        phaseZ<64, 384, true>(P.ellcv, P.nnz, P.h0, P.h1, P.ru, zb, b, s0, s1);
        phaseC<384, true>(zb, (const short8*)P.Wch[3], (const short8*)P.Wcl[3],
                          P.cb[3], P.ru, P.h1, b, P.pW, P.pb,
                          P.out + (size_t)hz * BN, P.dec_in);
        __syncthreads();
    }
}

// ---------------- host launcher ----------------

extern "C" void kernel_launch(void* const* d_in, const int* in_sizes, int n_in,
                              void* d_out, int out_size, void* d_ws, size_t ws_size,
                              hipStream_t stream)
{
    const float* inputs = (const float*)d_in[0];
    const float* S      = (const float*)d_in[1];
    const float* Wt[4][4];
    for (int l = 0; l < 4; ++l)
        for (int j = 0; j < 4; ++j)
            Wt[l][j] = (const float*)d_in[2 + l * 4 + j];
    const float* pW = (const float*)d_in[18];
    const float* pb = (const float*)d_in[19];
    float* out = (float*)d_out;

    // workspace layout
    float*    ws     = (float*)d_ws;
    float*    h0     = ws;                       // BN*U
    float*    h1     = h0 + BN * U;              // BN*U
    float*    dec_in = h1 + BN * U;              // BN
    float*    ru     = dec_in + BN;              // BN*128
    unsigned* zcat   = (unsigned*)(ru + BN * 128);   // 64 * ZBATCH (16B aligned)
    float2*   ellcv  = (float2*)(zcat + (size_t)B * ZBATCH);
    int*      nnz    = (int*)(ellcv + (size_t)ELLW * N);
    char*     wpbase = (char*)(nnz + ((N + 3) & ~3));
    wpbase = (char*)(((uintptr_t)wpbase + 15) & ~(uintptr_t)15);

    // layer geometry: K3 actual, K3p padded to 32
    const int K3s[4]  = {198, 384, 195, 384};
    const int K3ps[4] = {224, 384, 224, 384};
    short *Wgh[4], *Wgl[4], *Wch[4], *Wcl[4];
    size_t off = 0;
    for (int l = 0; l < 4; ++l) {
        const size_t ge = (size_t)K3ps[l] * 128, ce = (size_t)K3ps[l] * 64;
        Wgh[l] = (short*)(wpbase + off); off += ge * 2;
        Wgl[l] = (short*)(wpbase + off); off += ge * 2;
        Wch[l] = (short*)(wpbase + off); off += ce * 2;
        Wcl[l] = (short*)(wpbase + off); off += ce * 2;
    }

    ell_build<<<N, 64, 0, stream>>>(S, ellcv, nnz);
    for (int l = 0; l < 4; ++l) {
        prepack_w<<<dim3(K3ps[l] / 32, 8), 64, 0, stream>>>(Wt[l][0], Wgh[l], Wgl[l],
                                                            K3s[l], 128, 8);
        prepack_w<<<dim3(K3ps[l] / 32, 4), 64, 0, stream>>>(Wt[l][2], Wch[l], Wcl[l],
                                                            K3s[l], 64, 4);
    }

    MegaParams P;
    P.ellcv = ellcv; P.nnz = nnz; P.inputs = inputs;
    P.h0 = h0; P.h1 = h1; P.dec_in = dec_in; P.ru = ru; P.zcat = zcat;
    for (int l = 0; l < 4; ++l) {
        P.Wgh[l] = Wgh[l]; P.Wgl[l] = Wgl[l];
        P.Wch[l] = Wch[l]; P.Wcl[l] = Wcl[l];
        P.gb[l] = Wt[l][1]; P.cb[l] = Wt[l][3];
    }
    P.pW = pW; P.pb = pb; P.out = out;

    mega_kernel<<<B, BLK, 0, stream>>>(P);
}